// Round 21
// baseline (185.999 us; speedup 1.0000x reference)
//
#include <hip/hip_runtime.h>
#include <hip/hip_bf16.h>

// ---------------------------------------------------------------------------
// SparseKnowledgeAttention: q=ego@Wq.T+bq; k=(side*rel)@Wk.T+bk; v=side@Wv.T+bv
// scores=q@k.T/16 -> top16/row -> softmax -> weighted gather of v.
// Round 21 = round 20 with ONE change: scores_topk uses plain
// __launch_bounds__(256) (no min-waves arg).
//   Cross-round isolation: ",2"/",3" pin residency at ~2 blocks/CU
//   (r13/16/18/19/20: occ 20-26% despite LDS/VGPR headroom); ",4" raises
//   occupancy but shrinks the register budget -> Q remat (r15/r17, FETCH
//   50-170MB). Plain bounds: relaxed budget (VGPR ~108, no remat) + HW
//   packs to the LDS limit (50.2KB -> 3 blocks/CU).
//   Pass 1: NSPLIT=16, BN=64 (2 independent hi-only MFMA chains), CAP=16
//   u32 stack, packed-u32 keys (mono-f32 & ~0x1FFF) | (~gid & 0x1FFF).
//   proj: nt-loop split over grid (768 blocks).
//   Pass 2 (r15/r17/r18-verified): 256 partials -> top-20 by u32 max ->
//   16-lane-group parallel EXACT f32 rescore -> exact top-16 -> softmax ->
//   gather v.
// ---------------------------------------------------------------------------

#define EMB 256
#define NEGO 8192
#define NSIDE 8192
#define TOPKK 16
#define NSPLIT 16
#define SPLITLEN (NSIDE / NSPLIT)   // 512
#define BM 128                      // ego rows per block (4 waves x 32)
#define BN 64                       // side rows per group
#define NGRP (SPLITLEN / BN)        // 8 groups per block
#define CAP 16                      // stack capacity (alloc 17: slop slot)
#define RESCORE 20                  // approx superset rescored exactly

typedef _Float16 f16x8 __attribute__((ext_vector_type(8)));
typedef float f32x16 __attribute__((ext_vector_type(16)));

#define NEG_BIG (-3.402823466e38f)

__device__ __forceinline__ void gload_lds16(const _Float16* g, _Float16* l) {
    __builtin_amdgcn_global_load_lds((const __attribute__((address_space(1))) void*)g,
                                     (__attribute__((address_space(3))) void*)l, 16, 0, 0);
}

__device__ __forceinline__ void split8(const float* xv, f16x8& hi, f16x8& lo) {
#pragma unroll
    for (int j = 0; j < 8; ++j) {
        float x = xv[j];
        _Float16 h = (_Float16)x;
        hi[j] = h;
        lo[j] = (_Float16)(x - (float)h);
    }
}

// Monotone-u32 encoding of f32 (order-preserving), low 13 bits carry ~gid.
__device__ __forceinline__ unsigned packkey(float s, unsigned gid) {
    unsigned b = __float_as_uint(s);
    b = ((int)b >= 0) ? (b | 0x80000000u) : ~b;
    return (b & 0xFFFFE000u) | (gid ^ 0x1FFFu);
}

// ---------------------------------------------------------------------------
// Projection kernel: C = X @ W.T + b  via fp16x3 MFMA (exact). One output
// col-tile (nt = blockIdx.y) per block. z = blockIdx.z: 0:q, 1:k, 2:v.
// grid (64, 4, 3) = 768 blocks, block 256. Outputs: q,k as f16 hi/lo; v f32.
// ---------------------------------------------------------------------------
__global__ __launch_bounds__(256, 1) void proj_kernel(
    const float* __restrict__ ego, const float* __restrict__ side, const float* __restrict__ rel,
    const float* __restrict__ Wq, const float* __restrict__ bq,
    const float* __restrict__ Wk, const float* __restrict__ bk,
    const float* __restrict__ Wv, const float* __restrict__ bv,
    _Float16* __restrict__ qh, _Float16* __restrict__ ql,
    _Float16* __restrict__ kh, _Float16* __restrict__ kl,
    float* __restrict__ vout)
{
    __shared__ __align__(16) _Float16 Wh[64 * 256];   // 32KB, chunk-swizzled
    __shared__ __align__(16) _Float16 Wl[64 * 256];   // 32KB

    const int z = blockIdx.z;
    const int nt = blockIdx.y;
    const float* X; const float* W; const float* bias;
    if (z == 0)      { X = ego;  W = Wq; bias = bq; }
    else if (z == 1) { X = side; W = Wk; bias = bk; }
    else             { X = side; W = Wv; bias = bv; }

    const int tid = threadIdx.x, lane = tid & 63, wave = tid >> 6;
    const int hk = lane >> 5, r = lane & 31;
    const int arow = blockIdx.x * BM + wave * 32 + r;

    f16x8 ah[16], al[16];
#pragma unroll
    for (int kst = 0; kst < 16; ++kst) {
        float xv[8];
        const float* p = X + arow * EMB + kst * 16 + hk * 8;
        const float4 x0 = *(const float4*)p;
        const float4 x1 = *(const float4*)(p + 4);
        xv[0]=x0.x; xv[1]=x0.y; xv[2]=x0.z; xv[3]=x0.w;
        xv[4]=x1.x; xv[5]=x1.y; xv[6]=x1.z; xv[7]=x1.w;
        if (z == 1) {
            const float* pr = rel + arow * EMB + kst * 16 + hk * 8;
            const float4 r0 = *(const float4*)pr;
            const float4 r1 = *(const float4*)(pr + 4);
            xv[0]*=r0.x; xv[1]*=r0.y; xv[2]*=r0.z; xv[3]*=r0.w;
            xv[4]*=r1.x; xv[5]*=r1.y; xv[6]*=r1.z; xv[7]*=r1.w;
        }
        split8(xv, ah[kst], al[kst]);
    }

    // Stage W rows [nt*64, nt*64+64) into LDS, split + chunk-swizzled.
#pragma unroll
    for (int i = 0; i < 8; ++i) {
        const int rowi = wave * 16 + i * 2 + hk;
        const int c = r;
        const float* wp = W + (nt * 64 + rowi) * EMB + ((c ^ (rowi & 31)) << 3);
        float xv[8];
        const float4 w0 = *(const float4*)wp;
        const float4 w1 = *(const float4*)(wp + 4);
        xv[0]=w0.x; xv[1]=w0.y; xv[2]=w0.z; xv[3]=w0.w;
        xv[4]=w1.x; xv[5]=w1.y; xv[6]=w1.z; xv[7]=w1.w;
        f16x8 h8, l8;
        split8(xv, h8, l8);
        *(f16x8*)&Wh[rowi * 256 + c * 8] = h8;
        *(f16x8*)&Wl[rowi * 256 + c * 8] = l8;
    }
    __syncthreads();

    f32x16 acc0 = {}, acc1 = {};
#pragma unroll
    for (int kst = 0; kst < 16; ++kst) {
        const int cc = kst * 2 + hk;
        const f16x8 bh0 = *(const f16x8*)&Wh[r * 256 + ((cc ^ r) << 3)];
        const f16x8 bl0 = *(const f16x8*)&Wl[r * 256 + ((cc ^ r) << 3)];
        const f16x8 bh1 = *(const f16x8*)&Wh[(32 + r) * 256 + ((cc ^ r) << 3)];
        const f16x8 bl1 = *(const f16x8*)&Wl[(32 + r) * 256 + ((cc ^ r) << 3)];
        acc0 = __builtin_amdgcn_mfma_f32_32x32x16_f16(ah[kst], bh0, acc0, 0, 0, 0);
        acc0 = __builtin_amdgcn_mfma_f32_32x32x16_f16(al[kst], bh0, acc0, 0, 0, 0);
        acc0 = __builtin_amdgcn_mfma_f32_32x32x16_f16(ah[kst], bl0, acc0, 0, 0, 0);
        acc1 = __builtin_amdgcn_mfma_f32_32x32x16_f16(ah[kst], bh1, acc1, 0, 0, 0);
        acc1 = __builtin_amdgcn_mfma_f32_32x32x16_f16(al[kst], bh1, acc1, 0, 0, 0);
        acc1 = __builtin_amdgcn_mfma_f32_32x32x16_f16(ah[kst], bl1, acc1, 0, 0, 0);
    }

#pragma unroll
    for (int reg = 0; reg < 16; ++reg) {
        const int crow = (reg & 3) + 8 * (reg >> 2) + 4 * hk;
        const int grow = blockIdx.x * BM + wave * 32 + crow;
        const int col0 = nt * 64 + r;
        const int col1 = nt * 64 + 32 + r;
        const float v0 = acc0[reg] + bias[col0];
        const float v1 = acc1[reg] + bias[col1];
        if (z < 2) {
            _Float16* oh = (z == 0) ? qh : kh;
            _Float16* ol = (z == 0) ? ql : kl;
            _Float16 h0 = (_Float16)v0;
            oh[grow * EMB + col0] = h0;
            ol[grow * EMB + col0] = (_Float16)(v0 - (float)h0);
            _Float16 h1 = (_Float16)v1;
            oh[grow * EMB + col1] = h1;
            ol[grow * EMB + col1] = (_Float16)(v1 - (float)h1);
        } else {
            vout[grow * EMB + col0] = v0;
            vout[grow * EMB + col1] = v1;
        }
    }
}

// ---------------------------------------------------------------------------
// Pass 1: approx scores (Q-hi x K-hi) + per-split top-16 as packed u32 keys.
// grid 1024 (split = blk&15), block 256 (4 waves x 32 ego rows).
// BN=64 per group (2 independent MFMA chains), CAP=16 stack, LDS 49.4KB.
// Plain __launch_bounds__(256): relaxed VGPR budget (no remat) + HW packs
// blocks to the LDS limit (3/CU).
// ---------------------------------------------------------------------------
__global__ __launch_bounds__(256) void scores_topk_kernel(
    const _Float16* __restrict__ qh,
    const _Float16* __restrict__ kh,
    unsigned* __restrict__ part)
{
    __shared__ __align__(16) _Float16 Bh[BN * 256];   // 32KB k-tile (hi)
    __shared__ unsigned stk[(CAP + 1) * 256];         // 17.4KB survivor stacks

    const int tid = threadIdx.x, lane = tid & 63, wave = tid >> 6;
    const int hk = lane >> 5, r = lane & 31;
    const int split = blockIdx.x & 15;         // XCD-pinned K-split
    const int bx = blockIdx.x >> 4;            // ego block 0..63
    const int qbase = bx * BM + wave * 32;
    const int rowoff0 = 4 * hk;
    const int gidbase = split * SPLITLEN;

    // Per-lane register top-16 as packed u32 keys (unique: gid embedded).
    unsigned tk[16];
    unsigned curmin = 0u;

    // Q-hi fragments (row qbase+r) in registers — exact B-operand layout.
    f16x8 ah[16];
#pragma unroll
    for (int kst = 0; kst < 16; ++kst) {
        ah[kst] = *(const f16x8*)(qh + (qbase + r) * EMB + kst * 16 + hk * 8);
    }

    auto minTree = [&]() {
        unsigned m0 = min(tk[0], tk[1]),  m1 = min(tk[2], tk[3]);
        unsigned m2 = min(tk[4], tk[5]),  m3 = min(tk[6], tk[7]);
        unsigned m4 = min(tk[8], tk[9]),  m5 = min(tk[10], tk[11]);
        unsigned m6 = min(tk[12], tk[13]), m7 = min(tk[14], tk[15]);
        m0 = min(m0, m1); m2 = min(m2, m3); m4 = min(m4, m5); m6 = min(m6, m7);
        curmin = min(min(m0, m2), min(m4, m6));
    };

    auto insert = [&](unsigned k) {
        const bool p = k > curmin;
        const unsigned target = p ? curmin : 0xFFFFFFFFu;  // never matches when !p
#pragma unroll
        for (int j = 0; j < 16; ++j) {
            tk[j] = (tk[j] == target) ? k : tk[j];
        }
        minTree();
    };

    // Ballot-free drain: wave-max(cnt) once, counted loop, next-entry preload
    // (slop slot makes e+1 always in-bounds). Masked lanes feed key 0.
    int cnt = 0;
    auto rebuild = [&]() {
        int mc = cnt;
#pragma unroll
        for (int o = 32; o; o >>= 1) { const int t = __shfl_xor(mc, o); mc = t > mc ? t : mc; }
        unsigned v = stk[tid];
        for (int e = 0; e < mc; ++e) {
            const unsigned vn = stk[(e + 1) * 256 + tid];
            insert((e < cnt) ? v : 0u);
            v = vn;
        }
        cnt = 0;
    };

    // Filter 8 candidates from an accumulator quarter into the stack.
    auto filter8 = [&](const f32x16& acc, int q4, int base_col) {
#pragma unroll
        for (int jj = 0; jj < 8; ++jj) {
            const int j = q4 * 8 + jj;
            const unsigned gid = (unsigned)(base_col + (j & 3) + 8 * (j >> 2));
            const unsigned key = packkey(acc[j], gid);
            const bool p = key > curmin;
            stk[cnt * 256 + tid] = key;     // unconditional; slop slot
            cnt += p ? 1 : 0;
        }
    };

    for (int gi = 0; gi < NGRP; ++gi) {
        const int s0 = gidbase + gi * BN;
        // Stage 64-row K-hi tile (pre-swizzled source -> linear LDS dest
        // realizes chunk ^= (row&31): conflict-free ds_read_b128). r4 pattern.
#pragma unroll
        for (int i = 0; i < 8; ++i) {
            const int rho0 = wave * 16 + i * 2;    // covers rows rho0, rho0+1
            const int rho = rho0 + hk;
            const int gsrc = (s0 + rho) * EMB + ((r ^ (rho & 31)) << 3);
            gload_lds16(kh + gsrc, &Bh[rho0 * 256]);
        }
        __syncthreads();   // staged (compiler drains vmcnt before barrier)

        // Two INDEPENDENT hi*hi MFMA chains (rows r and 32+r of the tile).
        f32x16 acc0 = {}, acc1 = {};
#pragma unroll
        for (int kst = 0; kst < 16; ++kst) {
            const int slice = kst * 2 + hk;
            const f16x8 k0 = *(const f16x8*)&Bh[r * 256 + ((slice ^ r) << 3)];
            const f16x8 k1 = *(const f16x8*)&Bh[(32 + r) * 256 + ((slice ^ r) << 3)];
            acc0 = __builtin_amdgcn_mfma_f32_32x32x16_f16(k0, ah[kst], acc0, 0, 0, 0);
            acc1 = __builtin_amdgcn_mfma_f32_32x32x16_f16(k1, ah[kst], acc1, 0, 0, 0);
        }

        const int base0 = gidbase + gi * BN + rowoff0;
        const int base1 = base0 + 32;
        if (gi == 0) {
            // Fill from acc0's 16 directly; acc1 goes through the stack.
#pragma unroll
            for (int j = 0; j < 16; ++j) {
                const unsigned gid = (unsigned)(base0 + (j & 3) + 8 * (j >> 2));
                tk[j] = packkey(acc0[j], gid);
            }
            minTree();
            filter8(acc1, 0, base1);
            filter8(acc1, 1, base1);
            if (__any(cnt > 0)) rebuild();
        } else {
            filter8(acc0, 0, base0);
            filter8(acc0, 1, base0);
            if (__any(cnt > 0)) rebuild();
            filter8(acc1, 0, base1);
            filter8(acc1, 1, base1);
            if (__any(cnt > 0)) rebuild();
        }
        __syncthreads();   // all waves done reading Bh before restage
    }

    // Merge hk halves via SNAPSHOT (r10 fix): both lanes merge the partner's
    // ORIGINAL 16; candidate sets disjoint -> exact top-16 of the union.
    {
        unsigned osv[16];
#pragma unroll
        for (int j = 0; j < 16; ++j) osv[j] = (unsigned)__shfl_xor((int)tk[j], 32);
#pragma unroll
        for (int j = 0; j < 16; ++j) insert(osv[j]);
    }

    if (lane < 32) {
        const int row = qbase + r;
#pragma unroll
        for (int j = 0; j < 16; ++j) {
            part[(row * NSPLIT + split) * TOPKK + j] = tk[j];
        }
    }
}

// ---------------------------------------------------------------------------
// Pass 2: 256 packed partials/row -> approx top-20 (pure u32 max) -> EXACT
// parallel rescore (4 candidates x 16-lane groups, f32 (qh+ql).(kh+kl)) ->
// exact top-16 (score desc, id asc) -> softmax(/16) -> gather v.
// One wave per ego row (4 rows/block), 2048 blocks. (r15/r17/r18-verified.)
// ---------------------------------------------------------------------------
__global__ __launch_bounds__(256) void merge_kernel(
    const unsigned* __restrict__ part,
    const _Float16* __restrict__ qh, const _Float16* __restrict__ ql,
    const _Float16* __restrict__ kh, const _Float16* __restrict__ kl,
    const float* __restrict__ v, float* __restrict__ out)
{
    __shared__ int   isel[4][RESCORE];
    __shared__ float rsc[4][RESCORE];
    const int tid = threadIdx.x, lane = tid & 63, wave = tid >> 6;
    const int row = blockIdx.x * 4 + wave;

    unsigned c0 = part[row * 256 + lane];
    unsigned c1 = part[row * 256 + 64 + lane];
    unsigned c2 = part[row * 256 + 128 + lane];
    unsigned c3 = part[row * 256 + 192 + lane];

    // Approx top-20 extraction: single-u32 wave max (tie-break encoded).
    for (int t = 0; t < RESCORE; ++t) {
        unsigned bs = c0 > c1 ? c0 : c1;
        const unsigned b2 = c2 > c3 ? c2 : c3;
        bs = bs > b2 ? bs : b2;
#pragma unroll
        for (int o = 1; o < 64; o <<= 1) {
            const unsigned os = (unsigned)__shfl_xor((int)bs, o);
            bs = os > bs ? os : bs;
        }
        if (lane == 0) isel[wave][t] = (int)((bs & 0x1FFFu) ^ 0x1FFFu);
        c0 = (c0 == bs) ? 0u : c0;    // 0 == -inf (never a real packed value)
        c1 = (c1 == bs) ? 0u : c1;
        c2 = (c2 == bs) ? 0u : c2;
        c3 = (c3 == bs) ? 0u : c3;
    }
    __syncthreads();

    // Reconstruct q dims [gl*16, gl*16+16) for this row (q = qh + ql).
    const int g = lane >> 4, gl = lane & 15;
    float qr[16];
    {
        const f16x8 qa = *(const f16x8*)(qh + (size_t)row * EMB + gl * 16);
        const f16x8 qb = *(const f16x8*)(qh + (size_t)row * EMB + gl * 16 + 8);
        const f16x8 la = *(const f16x8*)(ql + (size_t)row * EMB + gl * 16);
        const f16x8 lb = *(const f16x8*)(ql + (size_t)row * EMB + gl * 16 + 8);
#pragma unroll
        for (int j = 0; j < 8; ++j) {
            qr[j]     = (float)qa[j] + (float)la[j];
            qr[8 + j] = (float)qb[j] + (float)lb[j];
        }
    }

    // Exact rescore: 4 candidates in parallel (one per 16-lane group).
#pragma unroll
    for (int rd = 0; rd < RESCORE / 4; ++rd) {
        const int cidx = rd * 4 + g;
        const int id = isel[wave][cidx];
        const f16x8 ka = *(const f16x8*)(kh + (size_t)id * EMB + gl * 16);
        const f16x8 kb = *(const f16x8*)(kh + (size_t)id * EMB + gl * 16 + 8);
        const f16x8 ma = *(const f16x8*)(kl + (size_t)id * EMB + gl * 16);
        const f16x8 mb = *(const f16x8*)(kl + (size_t)id * EMB + gl * 16 + 8);
        float p = 0.f;
#pragma unroll
        for (int j = 0; j < 8; ++j) {
            p = fmaf(qr[j],     (float)ka[j] + (float)ma[j], p);
            p = fmaf(qr[8 + j], (float)kb[j] + (float)mb[j], p);
        }
#pragma unroll
        for (int o = 1; o < 16; o <<= 1) p += __shfl_xor(p, o);   // 16-lane group sum
        if (gl == 0) rsc[wave][cidx] = p;
    }
    __syncthreads();

    // Exact top-16 of the 20 (score desc, id asc) + softmax weights.
    float es = (lane < RESCORE) ? rsc[wave][lane] : NEG_BIG;
    int  eid = (lane < RESCORE) ? isel[wave][lane] : 0x7fffffff;
    float w16[16]; int id16[16];
    float m = 0.f, denom = 0.f;
    for (int t = 0; t < 16; ++t) {
        float bs = es; int bid = eid;
#pragma unroll
        for (int o = 1; o < 64; o <<= 1) {
            const float os = __shfl_xor(bs, o);
            const int oid = __shfl_xor(bid, o);
            if (os > bs || (os == bs && oid < bid)) { bs = os; bid = oid; }
        }
        if (t == 0) m = bs;
        if (eid == bid) { es = NEG_BIG; eid = 0x7fffffff; }
        const float e = expf((bs - m) * 0.0625f);   // raw q.k scores; /16
        w16[t] = e; id16[t] = bid; denom += e;
    }
    const float inv = 1.0f / denom;

    float a0 = 0.f, a1 = 0.f, a2 = 0.f, a3 = 0.f;
#pragma unroll
    for (int t = 0; t < 16; ++t) {       // rank order == reference sum order
        const float w = w16[t] * inv;
        const float* vp = v + (long)id16[t] * EMB;
        a0 += w * vp[lane];
        a1 += w * vp[lane + 64];
        a2 += w * vp[lane + 128];
        a3 += w * vp[lane + 192];
    }
    out[row * EMB + lane]       = a0;
    out[row * EMB + lane + 64]  = a1;
    out[row * EMB + lane + 128] = a2;
    out[row * EMB + lane + 192] = a3;
}

// ---------------------------------------------------------------------------
extern "C" void kernel_launch(void* const* d_in, const int* in_sizes, int n_in,
                              void* d_out, int out_size, void* d_ws, size_t ws_size,
                              hipStream_t stream) {
    (void)in_sizes; (void)n_in; (void)out_size; (void)ws_size;
    const float* ego  = (const float*)d_in[0];
    const float* side = (const float*)d_in[1];
    const float* rel  = (const float*)d_in[2];
    const float* Wq   = (const float*)d_in[3];
    const float* bq   = (const float*)d_in[4];
    const float* Wk   = (const float*)d_in[5];
    const float* bk   = (const float*)d_in[6];
    const float* Wv   = (const float*)d_in[7];
    const float* bv   = (const float*)d_in[8];

    char* ws = (char*)d_ws;                      // 32MB used
    _Float16* qh = (_Float16*)ws;                // 4MB
    _Float16* ql = qh + (size_t)NEGO * EMB;      // 4MB
    _Float16* kh = ql + (size_t)NEGO * EMB;      // 4MB
    _Float16* kl = kh + (size_t)NSIDE * EMB;     // 4MB
    float*    vbuf = (float*)(ws + 16u * 1024 * 1024);      // 8MB
    unsigned* part = (unsigned*)(ws + 24u * 1024 * 1024);   // 8MB
    float* out = (float*)d_out;

    proj_kernel<<<dim3(NEGO / BM, 4, 3), dim3(256), 0, stream>>>(
        ego, side, rel, Wq, bq, Wk, bk, Wv, bv, qh, ql, kh, kl, vbuf);
    scores_topk_kernel<<<dim3(NEGO / BM * NSPLIT), dim3(256), 0, stream>>>(
        qh, kh, part);
    merge_kernel<<<dim3(NEGO / 4), dim3(256), 0, stream>>>(
        part, qh, ql, kh, kl, vbuf, out);
}

// Round 22
// 175.075 us; speedup vs baseline: 1.0624x; 1.0624x over previous
//
#include <hip/hip_runtime.h>
#include <hip/hip_bf16.h>

// ---------------------------------------------------------------------------
// SparseKnowledgeAttention: q=ego@Wq.T+bq; k=(side*rel)@Wk.T+bk; v=side@Wv.T+bv
// scores=q@k.T/16 -> top16/row -> softmax -> weighted gather of v.
// Round 22 = round 20 base (bounds(256,2), BN=64) with ONE change:
// CAP 16->32 and a SINGLE rebuild per group (was 2). Wave-max drain chains
// halve (16->8/pass) and sum-of-maxes shrinks (max is subadditive), cutting
// the dominant masked-insert VALU cost. LDS 65.8KB (unchanged residency).
//   Pass 1: NSPLIT=16, BN=64 (2 independent hi-only MFMA chains), u32 stack,
//   packed-u32 keys (mono-f32 & ~0x1FFF) | (~gid & 0x1FFF).
//   proj: nt-loop split over grid (768 blocks).
//   Pass 2 (r15/r17/r18-verified): 256 partials -> top-20 by u32 max ->
//   16-lane-group parallel EXACT f32 rescore -> exact top-16 -> softmax ->
//   gather v.
// ---------------------------------------------------------------------------

#define EMB 256
#define NEGO 8192
#define NSIDE 8192
#define TOPKK 16
#define NSPLIT 16
#define SPLITLEN (NSIDE / NSPLIT)   // 512
#define BM 128                      // ego rows per block (4 waves x 32)
#define BN 64                       // side rows per group
#define NGRP (SPLITLEN / BN)        // 8 groups per block
#define CAP 32                      // stack capacity (alloc 33: slop slot)
#define RESCORE 20                  // approx superset rescored exactly

typedef _Float16 f16x8 __attribute__((ext_vector_type(8)));
typedef float f32x16 __attribute__((ext_vector_type(16)));

#define NEG_BIG (-3.402823466e38f)

__device__ __forceinline__ void gload_lds16(const _Float16* g, _Float16* l) {
    __builtin_amdgcn_global_load_lds((const __attribute__((address_space(1))) void*)g,
                                     (__attribute__((address_space(3))) void*)l, 16, 0, 0);
}

__device__ __forceinline__ void split8(const float* xv, f16x8& hi, f16x8& lo) {
#pragma unroll
    for (int j = 0; j < 8; ++j) {
        float x = xv[j];
        _Float16 h = (_Float16)x;
        hi[j] = h;
        lo[j] = (_Float16)(x - (float)h);
    }
}

// Monotone-u32 encoding of f32 (order-preserving), low 13 bits carry ~gid.
__device__ __forceinline__ unsigned packkey(float s, unsigned gid) {
    unsigned b = __float_as_uint(s);
    b = ((int)b >= 0) ? (b | 0x80000000u) : ~b;
    return (b & 0xFFFFE000u) | (gid ^ 0x1FFFu);
}

// ---------------------------------------------------------------------------
// Projection kernel: C = X @ W.T + b  via fp16x3 MFMA (exact). One output
// col-tile (nt = blockIdx.y) per block. z = blockIdx.z: 0:q, 1:k, 2:v.
// grid (64, 4, 3) = 768 blocks, block 256. Outputs: q,k as f16 hi/lo; v f32.
// ---------------------------------------------------------------------------
__global__ __launch_bounds__(256, 1) void proj_kernel(
    const float* __restrict__ ego, const float* __restrict__ side, const float* __restrict__ rel,
    const float* __restrict__ Wq, const float* __restrict__ bq,
    const float* __restrict__ Wk, const float* __restrict__ bk,
    const float* __restrict__ Wv, const float* __restrict__ bv,
    _Float16* __restrict__ qh, _Float16* __restrict__ ql,
    _Float16* __restrict__ kh, _Float16* __restrict__ kl,
    float* __restrict__ vout)
{
    __shared__ __align__(16) _Float16 Wh[64 * 256];   // 32KB, chunk-swizzled
    __shared__ __align__(16) _Float16 Wl[64 * 256];   // 32KB

    const int z = blockIdx.z;
    const int nt = blockIdx.y;
    const float* X; const float* W; const float* bias;
    if (z == 0)      { X = ego;  W = Wq; bias = bq; }
    else if (z == 1) { X = side; W = Wk; bias = bk; }
    else             { X = side; W = Wv; bias = bv; }

    const int tid = threadIdx.x, lane = tid & 63, wave = tid >> 6;
    const int hk = lane >> 5, r = lane & 31;
    const int arow = blockIdx.x * BM + wave * 32 + r;

    f16x8 ah[16], al[16];
#pragma unroll
    for (int kst = 0; kst < 16; ++kst) {
        float xv[8];
        const float* p = X + arow * EMB + kst * 16 + hk * 8;
        const float4 x0 = *(const float4*)p;
        const float4 x1 = *(const float4*)(p + 4);
        xv[0]=x0.x; xv[1]=x0.y; xv[2]=x0.z; xv[3]=x0.w;
        xv[4]=x1.x; xv[5]=x1.y; xv[6]=x1.z; xv[7]=x1.w;
        if (z == 1) {
            const float* pr = rel + arow * EMB + kst * 16 + hk * 8;
            const float4 r0 = *(const float4*)pr;
            const float4 r1 = *(const float4*)(pr + 4);
            xv[0]*=r0.x; xv[1]*=r0.y; xv[2]*=r0.z; xv[3]*=r0.w;
            xv[4]*=r1.x; xv[5]*=r1.y; xv[6]*=r1.z; xv[7]*=r1.w;
        }
        split8(xv, ah[kst], al[kst]);
    }

    // Stage W rows [nt*64, nt*64+64) into LDS, split + chunk-swizzled.
#pragma unroll
    for (int i = 0; i < 8; ++i) {
        const int rowi = wave * 16 + i * 2 + hk;
        const int c = r;
        const float* wp = W + (nt * 64 + rowi) * EMB + ((c ^ (rowi & 31)) << 3);
        float xv[8];
        const float4 w0 = *(const float4*)wp;
        const float4 w1 = *(const float4*)(wp + 4);
        xv[0]=w0.x; xv[1]=w0.y; xv[2]=w0.z; xv[3]=w0.w;
        xv[4]=w1.x; xv[5]=w1.y; xv[6]=w1.z; xv[7]=w1.w;
        f16x8 h8, l8;
        split8(xv, h8, l8);
        *(f16x8*)&Wh[rowi * 256 + c * 8] = h8;
        *(f16x8*)&Wl[rowi * 256 + c * 8] = l8;
    }
    __syncthreads();

    f32x16 acc0 = {}, acc1 = {};
#pragma unroll
    for (int kst = 0; kst < 16; ++kst) {
        const int cc = kst * 2 + hk;
        const f16x8 bh0 = *(const f16x8*)&Wh[r * 256 + ((cc ^ r) << 3)];
        const f16x8 bl0 = *(const f16x8*)&Wl[r * 256 + ((cc ^ r) << 3)];
        const f16x8 bh1 = *(const f16x8*)&Wh[(32 + r) * 256 + ((cc ^ r) << 3)];
        const f16x8 bl1 = *(const f16x8*)&Wl[(32 + r) * 256 + ((cc ^ r) << 3)];
        acc0 = __builtin_amdgcn_mfma_f32_32x32x16_f16(ah[kst], bh0, acc0, 0, 0, 0);
        acc0 = __builtin_amdgcn_mfma_f32_32x32x16_f16(al[kst], bh0, acc0, 0, 0, 0);
        acc0 = __builtin_amdgcn_mfma_f32_32x32x16_f16(ah[kst], bl0, acc0, 0, 0, 0);
        acc1 = __builtin_amdgcn_mfma_f32_32x32x16_f16(ah[kst], bh1, acc1, 0, 0, 0);
        acc1 = __builtin_amdgcn_mfma_f32_32x32x16_f16(al[kst], bh1, acc1, 0, 0, 0);
        acc1 = __builtin_amdgcn_mfma_f32_32x32x16_f16(ah[kst], bl1, acc1, 0, 0, 0);
    }

#pragma unroll
    for (int reg = 0; reg < 16; ++reg) {
        const int crow = (reg & 3) + 8 * (reg >> 2) + 4 * hk;
        const int grow = blockIdx.x * BM + wave * 32 + crow;
        const int col0 = nt * 64 + r;
        const int col1 = nt * 64 + 32 + r;
        const float v0 = acc0[reg] + bias[col0];
        const float v1 = acc1[reg] + bias[col1];
        if (z < 2) {
            _Float16* oh = (z == 0) ? qh : kh;
            _Float16* ol = (z == 0) ? ql : kl;
            _Float16 h0 = (_Float16)v0;
            oh[grow * EMB + col0] = h0;
            ol[grow * EMB + col0] = (_Float16)(v0 - (float)h0);
            _Float16 h1 = (_Float16)v1;
            oh[grow * EMB + col1] = h1;
            ol[grow * EMB + col1] = (_Float16)(v1 - (float)h1);
        } else {
            vout[grow * EMB + col0] = v0;
            vout[grow * EMB + col1] = v1;
        }
    }
}

// ---------------------------------------------------------------------------
// Pass 1: approx scores (Q-hi x K-hi) + per-split top-16 as packed u32 keys.
// grid 1024 (split = blk&15), block 256 (4 waves x 32 ego rows).
// BN=64 per group (2 independent MFMA chains), CAP=32 stack, ONE rebuild
// per group. LDS 65.8KB.
// ---------------------------------------------------------------------------
__global__ __launch_bounds__(256, 2) void scores_topk_kernel(
    const _Float16* __restrict__ qh,
    const _Float16* __restrict__ kh,
    unsigned* __restrict__ part)
{
    __shared__ __align__(16) _Float16 Bh[BN * 256];   // 32KB k-tile (hi)
    __shared__ unsigned stk[(CAP + 1) * 256];         // 33.8KB survivor stacks

    const int tid = threadIdx.x, lane = tid & 63, wave = tid >> 6;
    const int hk = lane >> 5, r = lane & 31;
    const int split = blockIdx.x & 15;         // XCD-pinned K-split
    const int bx = blockIdx.x >> 4;            // ego block 0..63
    const int qbase = bx * BM + wave * 32;
    const int rowoff0 = 4 * hk;
    const int gidbase = split * SPLITLEN;

    // Per-lane register top-16 as packed u32 keys (unique: gid embedded).
    unsigned tk[16];
    unsigned curmin = 0u;

    // Q-hi fragments (row qbase+r) in registers — exact B-operand layout.
    f16x8 ah[16];
#pragma unroll
    for (int kst = 0; kst < 16; ++kst) {
        ah[kst] = *(const f16x8*)(qh + (qbase + r) * EMB + kst * 16 + hk * 8);
    }

    auto minTree = [&]() {
        unsigned m0 = min(tk[0], tk[1]),  m1 = min(tk[2], tk[3]);
        unsigned m2 = min(tk[4], tk[5]),  m3 = min(tk[6], tk[7]);
        unsigned m4 = min(tk[8], tk[9]),  m5 = min(tk[10], tk[11]);
        unsigned m6 = min(tk[12], tk[13]), m7 = min(tk[14], tk[15]);
        m0 = min(m0, m1); m2 = min(m2, m3); m4 = min(m4, m5); m6 = min(m6, m7);
        curmin = min(min(m0, m2), min(m4, m6));
    };

    auto insert = [&](unsigned k) {
        const bool p = k > curmin;
        const unsigned target = p ? curmin : 0xFFFFFFFFu;  // never matches when !p
#pragma unroll
        for (int j = 0; j < 16; ++j) {
            tk[j] = (tk[j] == target) ? k : tk[j];
        }
        minTree();
    };

    // Ballot-free drain: wave-max(cnt) once, counted loop, next-entry preload
    // (slop slot makes e+1 always in-bounds). Masked lanes feed key 0.
    int cnt = 0;
    auto rebuild = [&]() {
        int mc = cnt;
#pragma unroll
        for (int o = 32; o; o >>= 1) { const int t = __shfl_xor(mc, o); mc = t > mc ? t : mc; }
        unsigned v = stk[tid];
        for (int e = 0; e < mc; ++e) {
            const unsigned vn = stk[(e + 1) * 256 + tid];
            insert((e < cnt) ? v : 0u);
            v = vn;
        }
        cnt = 0;
    };

    // Filter 8 candidates from an accumulator quarter into the stack.
    auto filter8 = [&](const f32x16& acc, int q4, int base_col) {
#pragma unroll
        for (int jj = 0; jj < 8; ++jj) {
            const int j = q4 * 8 + jj;
            const unsigned gid = (unsigned)(base_col + (j & 3) + 8 * (j >> 2));
            const unsigned key = packkey(acc[j], gid);
            const bool p = key > curmin;
            stk[cnt * 256 + tid] = key;     // unconditional; slop slot
            cnt += p ? 1 : 0;
        }
    };

    for (int gi = 0; gi < NGRP; ++gi) {
        const int s0 = gidbase + gi * BN;
        // Stage 64-row K-hi tile (pre-swizzled source -> linear LDS dest
        // realizes chunk ^= (row&31): conflict-free ds_read_b128). r4 pattern.
#pragma unroll
        for (int i = 0; i < 8; ++i) {
            const int rho0 = wave * 16 + i * 2;    // covers rows rho0, rho0+1
            const int rho = rho0 + hk;
            const int gsrc = (s0 + rho) * EMB + ((r ^ (rho & 31)) << 3);
            gload_lds16(kh + gsrc, &Bh[rho0 * 256]);
        }
        __syncthreads();   // staged (compiler drains vmcnt before barrier)

        // Two INDEPENDENT hi*hi MFMA chains (rows r and 32+r of the tile).
        f32x16 acc0 = {}, acc1 = {};
#pragma unroll
        for (int kst = 0; kst < 16; ++kst) {
            const int slice = kst * 2 + hk;
            const f16x8 k0 = *(const f16x8*)&Bh[r * 256 + ((slice ^ r) << 3)];
            const f16x8 k1 = *(const f16x8*)&Bh[(32 + r) * 256 + ((slice ^ r) << 3)];
            acc0 = __builtin_amdgcn_mfma_f32_32x32x16_f16(k0, ah[kst], acc0, 0, 0, 0);
            acc1 = __builtin_amdgcn_mfma_f32_32x32x16_f16(k1, ah[kst], acc1, 0, 0, 0);
        }

        const int base0 = gidbase + gi * BN + rowoff0;
        const int base1 = base0 + 32;
        if (gi == 0) {
            // Fill from acc0's 16 directly; acc1 goes through the stack.
#pragma unroll
            for (int j = 0; j < 16; ++j) {
                const unsigned gid = (unsigned)(base0 + (j & 3) + 8 * (j >> 2));
                tk[j] = packkey(acc0[j], gid);
            }
            minTree();
            filter8(acc1, 0, base1);
            filter8(acc1, 1, base1);
            if (__any(cnt > 0)) rebuild();
        } else {
            // All 64 candidates filtered first; ONE drain per group
            // (max is subadditive: fewer masked no-op inserts than 2 drains).
            filter8(acc0, 0, base0);
            filter8(acc0, 1, base0);
            filter8(acc1, 0, base1);
            filter8(acc1, 1, base1);
            if (__any(cnt > 0)) rebuild();
        }
        __syncthreads();   // all waves done reading Bh before restage
    }

    // Merge hk halves via SNAPSHOT (r10 fix): both lanes merge the partner's
    // ORIGINAL 16; candidate sets disjoint -> exact top-16 of the union.
    {
        unsigned osv[16];
#pragma unroll
        for (int j = 0; j < 16; ++j) osv[j] = (unsigned)__shfl_xor((int)tk[j], 32);
#pragma unroll
        for (int j = 0; j < 16; ++j) insert(osv[j]);
    }

    if (lane < 32) {
        const int row = qbase + r;
#pragma unroll
        for (int j = 0; j < 16; ++j) {
            part[(row * NSPLIT + split) * TOPKK + j] = tk[j];
        }
    }
}

// ---------------------------------------------------------------------------
// Pass 2: 256 packed partials/row -> approx top-20 (pure u32 max) -> EXACT
// parallel rescore (4 candidates x 16-lane groups, f32 (qh+ql).(kh+kl)) ->
// exact top-16 (score desc, id asc) -> softmax(/16) -> gather v.
// One wave per ego row (4 rows/block), 2048 blocks. (r15/r17/r18-verified.)
// ---------------------------------------------------------------------------
__global__ __launch_bounds__(256) void merge_kernel(
    const unsigned* __restrict__ part,
    const _Float16* __restrict__ qh, const _Float16* __restrict__ ql,
    const _Float16* __restrict__ kh, const _Float16* __restrict__ kl,
    const float* __restrict__ v, float* __restrict__ out)
{
    __shared__ int   isel[4][RESCORE];
    __shared__ float rsc[4][RESCORE];
    const int tid = threadIdx.x, lane = tid & 63, wave = tid >> 6;
    const int row = blockIdx.x * 4 + wave;

    unsigned c0 = part[row * 256 + lane];
    unsigned c1 = part[row * 256 + 64 + lane];
    unsigned c2 = part[row * 256 + 128 + lane];
    unsigned c3 = part[row * 256 + 192 + lane];

    // Approx top-20 extraction: single-u32 wave max (tie-break encoded).
    for (int t = 0; t < RESCORE; ++t) {
        unsigned bs = c0 > c1 ? c0 : c1;
        const unsigned b2 = c2 > c3 ? c2 : c3;
        bs = bs > b2 ? bs : b2;
#pragma unroll
        for (int o = 1; o < 64; o <<= 1) {
            const unsigned os = (unsigned)__shfl_xor((int)bs, o);
            bs = os > bs ? os : bs;
        }
        if (lane == 0) isel[wave][t] = (int)((bs & 0x1FFFu) ^ 0x1FFFu);
        c0 = (c0 == bs) ? 0u : c0;    // 0 == -inf (never a real packed value)
        c1 = (c1 == bs) ? 0u : c1;
        c2 = (c2 == bs) ? 0u : c2;
        c3 = (c3 == bs) ? 0u : c3;
    }
    __syncthreads();

    // Reconstruct q dims [gl*16, gl*16+16) for this row (q = qh + ql).
    const int g = lane >> 4, gl = lane & 15;
    float qr[16];
    {
        const f16x8 qa = *(const f16x8*)(qh + (size_t)row * EMB + gl * 16);
        const f16x8 qb = *(const f16x8*)(qh + (size_t)row * EMB + gl * 16 + 8);
        const f16x8 la = *(const f16x8*)(ql + (size_t)row * EMB + gl * 16);
        const f16x8 lb = *(const f16x8*)(ql + (size_t)row * EMB + gl * 16 + 8);
#pragma unroll
        for (int j = 0; j < 8; ++j) {
            qr[j]     = (float)qa[j] + (float)la[j];
            qr[8 + j] = (float)qb[j] + (float)lb[j];
        }
    }

    // Exact rescore: 4 candidates in parallel (one per 16-lane group).
#pragma unroll
    for (int rd = 0; rd < RESCORE / 4; ++rd) {
        const int cidx = rd * 4 + g;
        const int id = isel[wave][cidx];
        const f16x8 ka = *(const f16x8*)(kh + (size_t)id * EMB + gl * 16);
        const f16x8 kb = *(const f16x8*)(kh + (size_t)id * EMB + gl * 16 + 8);
        const f16x8 ma = *(const f16x8*)(kl + (size_t)id * EMB + gl * 16);
        const f16x8 mb = *(const f16x8*)(kl + (size_t)id * EMB + gl * 16 + 8);
        float p = 0.f;
#pragma unroll
        for (int j = 0; j < 8; ++j) {
            p = fmaf(qr[j],     (float)ka[j] + (float)ma[j], p);
            p = fmaf(qr[8 + j], (float)kb[j] + (float)mb[j], p);
        }
#pragma unroll
        for (int o = 1; o < 16; o <<= 1) p += __shfl_xor(p, o);   // 16-lane group sum
        if (gl == 0) rsc[wave][cidx] = p;
    }
    __syncthreads();

    // Exact top-16 of the 20 (score desc, id asc) + softmax weights.
    float es = (lane < RESCORE) ? rsc[wave][lane] : NEG_BIG;
    int  eid = (lane < RESCORE) ? isel[wave][lane] : 0x7fffffff;
    float w16[16]; int id16[16];
    float m = 0.f, denom = 0.f;
    for (int t = 0; t < 16; ++t) {
        float bs = es; int bid = eid;
#pragma unroll
        for (int o = 1; o < 64; o <<= 1) {
            const float os = __shfl_xor(bs, o);
            const int oid = __shfl_xor(bid, o);
            if (os > bs || (os == bs && oid < bid)) { bs = os; bid = oid; }
        }
        if (t == 0) m = bs;
        if (eid == bid) { es = NEG_BIG; eid = 0x7fffffff; }
        const float e = expf((bs - m) * 0.0625f);   // raw q.k scores; /16
        w16[t] = e; id16[t] = bid; denom += e;
    }
    const float inv = 1.0f / denom;

    float a0 = 0.f, a1 = 0.f, a2 = 0.f, a3 = 0.f;
#pragma unroll
    for (int t = 0; t < 16; ++t) {       // rank order == reference sum order
        const float w = w16[t] * inv;
        const float* vp = v + (long)id16[t] * EMB;
        a0 += w * vp[lane];
        a1 += w * vp[lane + 64];
        a2 += w * vp[lane + 128];
        a3 += w * vp[lane + 192];
    }
    out[row * EMB + lane]       = a0;
    out[row * EMB + lane + 64]  = a1;
    out[row * EMB + lane + 128] = a2;
    out[row * EMB + lane + 192] = a3;
}

// ---------------------------------------------------------------------------
extern "C" void kernel_launch(void* const* d_in, const int* in_sizes, int n_in,
                              void* d_out, int out_size, void* d_ws, size_t ws_size,
                              hipStream_t stream) {
    (void)in_sizes; (void)n_in; (void)out_size; (void)ws_size;
    const float* ego  = (const float*)d_in[0];
    const float* side = (const float*)d_in[1];
    const float* rel  = (const float*)d_in[2];
    const float* Wq   = (const float*)d_in[3];
    const float* bq   = (const float*)d_in[4];
    const float* Wk   = (const float*)d_in[5];
    const float* bk   = (const float*)d_in[6];
    const float* Wv   = (const float*)d_in[7];
    const float* bv   = (const float*)d_in[8];

    char* ws = (char*)d_ws;                      // 32MB used
    _Float16* qh = (_Float16*)ws;                // 4MB
    _Float16* ql = qh + (size_t)NEGO * EMB;      // 4MB
    _Float16* kh = ql + (size_t)NEGO * EMB;      // 4MB
    _Float16* kl = kh + (size_t)NSIDE * EMB;     // 4MB
    float*    vbuf = (float*)(ws + 16u * 1024 * 1024);      // 8MB
    unsigned* part = (unsigned*)(ws + 24u * 1024 * 1024);   // 8MB
    float* out = (float*)d_out;

    proj_kernel<<<dim3(NEGO / BM, 4, 3), dim3(256), 0, stream>>>(
        ego, side, rel, Wq, bq, Wk, bk, Wv, bv, qh, ql, kh, kl, vbuf);
    scores_topk_kernel<<<dim3(NEGO / BM * NSPLIT), dim3(256), 0, stream>>>(
        qh, kh, part);
    merge_kernel<<<dim3(NEGO / 4), dim3(256), 0, stream>>>(
        part, qh, ql, kh, kl, vbuf, out);
}